// Round 7
// baseline (170.084 us; speedup 1.0000x reference)
//
#include <hip/hip_runtime.h>
#include <hip/hip_bf16.h>
#include <math.h>

// Problem constants
#define BB   32
#define HN   12
#define N1   256
#define N2   320
#define SS   256
#define BH   (BB*HN)                 // 384
#define ROWS (BH*N1)                 // 98304 rows per tensor
#define R4   (N2/4)                  // 80 float4 per row
#define N4PT ((size_t)ROWS*R4)       // float4 per tensor = 7,864,320

typedef float v4f __attribute__((ext_vector_type(4)));

// ---------------- K1: rowmax, grid-strided, 4-row load batches --------------
#define K1_BLOCKS 2048
#define K1_WAVES  (K1_BLOCKS*4)             // 8192
#define ROWS_TOTAL (2*ROWS)                 // 196608
#define RPW (ROWS_TOTAL/K1_WAVES)           // 24 rows per wave

__global__ __launch_bounds__(256) void k_rowmax(
    const float* __restrict__ rgb, const float* __restrict__ tir,
    float* __restrict__ mxr, float* __restrict__ mxt)
{
    const int gw   = ((int)blockIdx.x * 256 + (int)threadIdx.x) >> 6;
    const int lane = threadIdx.x & 63;
    const int base = gw * RPW;

    for (int rr = 0; rr < RPW; rr += 4) {
        v4f a[4], b[4];
#pragma unroll
        for (int q = 0; q < 4; ++q) {
            int row   = base + rr + q;            // 0..ROWS_TOTAL
            int isTir = row >= ROWS;
            int r     = isTir ? row - ROWS : row;
            const v4f* p = (const v4f*)((isTir ? tir : rgb) + (size_t)r * N2);
            a[q] = p[lane];
            // tail f4s [64,80): duplicated across lanes (no effect on max,
            // duplicate addresses coalesce to the same lines)
            b[q] = p[64 + (lane & 15)];
        }
#pragma unroll
        for (int q = 0; q < 4; ++q) {
            float m = fmaxf(fmaxf(fmaxf(a[q].x, a[q].y), fmaxf(a[q].z, a[q].w)),
                            fmaxf(fmaxf(b[q].x, b[q].y), fmaxf(b[q].z, b[q].w)));
#pragma unroll
            for (int off = 32; off; off >>= 1) m = fmaxf(m, __shfl_xor(m, off));
            if (lane == 0) {
                int row   = base + rr + q;
                int isTir = row >= ROWS;
                int r     = isTir ? row - ROWS : row;
                (isTir ? mxt : mxr)[r] = m;
            }
        }
    }
}

// ---------------- K2: scatter -> LN(512) -> MLP -> gather gates -------------
// one block per (b,h); weights (1 MB) are L2-resident and shared.
__global__ __launch_bounds__(256) void k_mlp(
    const int*   __restrict__ gidx,
    const float* __restrict__ mxr, const float* __restrict__ mxt,
    const float* __restrict__ ln_g, const float* __restrict__ ln_b,
    const float* __restrict__ W1,  const float* __restrict__ b1,
    const float* __restrict__ W2,  const float* __restrict__ b2,
    float* __restrict__ growR, float* __restrict__ growT)
{
    __shared__ float v[2 * SS];
    __shared__ float hs[SS];
    __shared__ float gs[2 * SS];
    __shared__ int   sidx_s[SS];
    __shared__ float red[8];

    const int bh   = (int)blockIdx.x;    // 0..383
    const int b    = bh / HN;
    const int t    = (int)threadIdx.x;   // 0..255
    const int w    = t >> 6;
    const int lane = t & 63;

    sidx_s[t] = gidx[b * SS + t];
    v[t] = 0.f; v[t + SS] = 0.f;
    __syncthreads();

    // scatter (per-batch permutation -> collision-free)
    {
        int sidx = sidx_s[t];
        v[sidx]      = mxr[bh * N1 + t];
        v[sidx + SS] = mxt[bh * N1 + t];
    }
    __syncthreads();

    // LayerNorm over 512
    {
        float x0 = v[t], x1 = v[t + SS];
        float s  = x0 + x1;
        float sq = x0 * x0 + x1 * x1;
#pragma unroll
        for (int off = 32; off; off >>= 1) {
            s  += __shfl_xor(s, off);
            sq += __shfl_xor(sq, off);
        }
        if (lane == 0) { red[w] = s; red[4 + w] = sq; }
        __syncthreads();
        s  = red[0] + red[1] + red[2] + red[3];
        sq = red[4] + red[5] + red[6] + red[7];
        const float mu   = s * (1.f / 512.f);
        const float var  = sq * (1.f / 512.f) - mu * mu;
        const float rstd = rsqrtf(var + 1e-5f);
        v[t]      = (x0 - mu) * rstd * ln_g[t]      + ln_b[t];
        v[t + SS] = (x1 - mu) * rstd * ln_g[t + SS] + ln_b[t + SS];
    }
    __syncthreads();

    // GEMM1: hs[t] = relu(sum_e v[e]*W1[e*256+t] + b1[t])
    {
        float a0 = b1[t], a1 = 0.f;
#pragma unroll 8
        for (int e = 0; e < SS; ++e)       a0 = fmaf(v[e], W1[e * SS + t], a0);
#pragma unroll 8
        for (int e = SS; e < 2 * SS; ++e)  a1 = fmaf(v[e], W1[e * SS + t], a1);
        hs[t] = fmaxf(a0 + a1, 0.f);
    }
    __syncthreads();

    // GEMM2: gs[.] = sigmoid(sum_f hs[f]*W2[f*512+.] + b2)
    {
        float lo0 = b2[t], lo1 = 0.f, hi0 = b2[t + SS], hi1 = 0.f;
#pragma unroll 8
        for (int f = 0; f < 128; ++f) {
            float hv = hs[f];
            lo0 = fmaf(hv, W2[f * 2 * SS + t],      lo0);
            hi0 = fmaf(hv, W2[f * 2 * SS + t + SS], hi0);
        }
#pragma unroll 8
        for (int f = 128; f < SS; ++f) {
            float hv = hs[f];
            lo1 = fmaf(hv, W2[f * 2 * SS + t],      lo1);
            hi1 = fmaf(hv, W2[f * 2 * SS + t + SS], hi1);
        }
        gs[t]      = 1.f / (1.f + expf(-(lo0 + lo1)));
        gs[t + SS] = 1.f / (1.f + expf(-(hi0 + hi1)));
    }
    __syncthreads();

    // gather per-row gates to (b,h,n1) order
    growR[bh * N1 + t] = gs[sidx_s[t]];
    growT[bh * N1 + t] = gs[sidx_s[t] + SS];
}

// ---------------- K3: modulate, 8 f4/thread, NT stores ----------------------
// N4PT = 2048*3840 exactly: blocks [0,3840) are pure-tir, [3840,7680) pure-rgb.
#define K3_HALF 3840
#define K3_BLOCKS (2*K3_HALF)

__global__ __launch_bounds__(256) void k_mod(
    const float* __restrict__ rgb, const float* __restrict__ tir,
    const float* __restrict__ growR, const float* __restrict__ growT,
    v4f* __restrict__ outTir, v4f* __restrict__ outRgb)
{
    const int blk   = (int)blockIdx.x;
    const int isRgb = blk >= K3_HALF;
    const v4f*   src  = (const v4f*)(isRgb ? rgb : tir);
    const float* grow = isRgb ? growR : growT;
    v4f*         dst  = isRgb ? outRgb : outTir;

    const unsigned j0 = (unsigned)(isRgb ? blk - K3_HALF : blk) * 2048u
                      + (unsigned)threadIdx.x;
    v4f a[8];
#pragma unroll
    for (int q = 0; q < 8; ++q) a[q] = src[j0 + q * 256u];
    float g[8];
#pragma unroll
    for (int q = 0; q < 8; ++q) g[q] = grow[(j0 + q * 256u) / 80u];
#pragma unroll
    for (int q = 0; q < 8; ++q)
        __builtin_nontemporal_store(a[q] * g[q], &dst[j0 + q * 256u]);
}

extern "C" void kernel_launch(void* const* d_in, const int* in_sizes, int n_in,
                              void* d_out, int out_size, void* d_ws, size_t ws_size,
                              hipStream_t stream)
{
    const float* attn_rgb = (const float*)d_in[0];
    const float* attn_tir = (const float*)d_in[1];
    const int*   gidx     = (const int*)  d_in[2];
    const float* ln_g     = (const float*)d_in[3];
    const float* ln_b     = (const float*)d_in[4];
    const float* W1       = (const float*)d_in[5];
    const float* b1       = (const float*)d_in[6];
    const float* W2       = (const float*)d_in[7];
    const float* b2       = (const float*)d_in[8];

    float* ws    = (float*)d_ws;
    float* mxr   = ws;                 // [ROWS]
    float* mxt   = mxr + ROWS;         // [ROWS]
    float* growR = mxt + ROWS;         // [ROWS]
    float* growT = growR + ROWS;       // [ROWS]

    v4f* outTir = (v4f*)d_out;         // tir_col first per reference return
    v4f* outRgb = outTir + N4PT;

    k_rowmax<<<K1_BLOCKS, 256, 0, stream>>>(attn_rgb, attn_tir, mxr, mxt);

    k_mlp<<<BH, 256, 0, stream>>>(gidx, mxr, mxt, ln_g, ln_b,
                                  W1, b1, W2, b2, growR, growT);

    k_mod<<<K3_BLOCKS, 256, 0, stream>>>(attn_rgb, attn_tir, growR, growT,
                                         outTir, outRgb);
}